// Round 9
// baseline (185.282 us; speedup 1.0000x reference)
//
#include <hip/hip_runtime.h>
#include <hip/hip_bf16.h>

using bf16 = __hip_bfloat16;
typedef __attribute__((ext_vector_type(8))) short bf16x8;
typedef __attribute__((ext_vector_type(4))) short bf16x4;
typedef __attribute__((ext_vector_type(4))) float f32x4;
typedef __attribute__((ext_vector_type(16))) float f32x16;

static constexpr int Bb = 4, Ss = 2048, Dd = 1024, Hh = 16, HD = 64;
static constexpr int TD = 3 * Dd;            // 3072
static constexpr int Mrows = Bb * Ss;        // 8192

#define MFMA16(a, b, c) __builtin_amdgcn_mfma_f32_16x16x32_bf16((a), (b), (c), 0, 0, 0)
#define MFMA32(a, b, c) __builtin_amdgcn_mfma_f32_32x32x16_bf16((a), (b), (c), 0, 0, 0)

__device__ __forceinline__ void gload_lds16(const void* g, void* l) {
    __builtin_amdgcn_global_load_lds(
        (const __attribute__((address_space(1))) void*)g,
        (__attribute__((address_space(3))) void*)l, 16, 0, 0);
}

__device__ __forceinline__ unsigned lds_addr(const void* p) {
    return (unsigned)(unsigned long long)(const __attribute__((address_space(3))) char*)p;
}

__device__ __forceinline__ unsigned pack2bf(float a, float b) {
    bf16 x = __float2bfloat16(a), y = __float2bfloat16(b);
    return (unsigned)(*(unsigned short*)&x) | ((unsigned)(*(unsigned short*)&y) << 16);
}

// ---------------- cast fp32 -> bf16, 4 elems/thread ----------------
__global__ void cast_f32_bf16(const float* __restrict__ in, bf16* __restrict__ out, int n4) {
    int i = blockIdx.x * blockDim.x + threadIdx.x;
    if (i >= n4) return;
    float4 v = ((const float4*)in)[i];
    bf16 t0 = __float2bfloat16(v.x), t1 = __float2bfloat16(v.y);
    bf16 t2 = __float2bfloat16(v.z), t3 = __float2bfloat16(v.w);
    unsigned int lo = (unsigned int)(*(unsigned short*)&t0) | ((unsigned int)(*(unsigned short*)&t1) << 16);
    unsigned int hi = (unsigned int)(*(unsigned short*)&t2) | ((unsigned int)(*(unsigned short*)&t3) << 16);
    uint2 o; o.x = lo; o.y = hi;
    *(uint2*)(out + 4l * i) = o;
}

// ---------------- GEMM 256x256, BK=64, 8 waves, m201 8-phase schedule ------
// Per K-tile group g (buf b=g&1): 4 phases of {ds_reads; s_barrier;
// lgkmcnt(0); setprio(1); 16 MFMA; setprio(0); s_barrier}. Read sets
// 12/4/8/0 b128 (fragment-reuse rotation Q0->Q1->Q2->Q3). Phase 3 stages
// K-tile g+2 into buf b (freed by ph2's trailing barrier) and waits
// vmcnt(8) -- counted, never 0: drains exactly K-tile g+1's loads.
// T2: XOR-swizzled LDS via pre-swizzled global_load_lds source.
// Raw s_barrier everywhere (no __syncthreads: it drains vmcnt(0)).
template<bool OUT_BF16>
__global__ __launch_bounds__(512, 1) void gemm256(
    const bf16* __restrict__ A, const bf16* __restrict__ Bt,
    bf16* __restrict__ Cb, float* __restrict__ Cf, const float* __restrict__ bias,
    int M, int N, int K)
{
    __shared__ __align__(16) bf16 As[2][256 * 64];   // 64 KB
    __shared__ __align__(16) bf16 Bs[2][256 * 64];   // 64 KB
    const int tid = threadIdx.x;
    const int lane = tid & 63;
    const int wid = tid >> 6;
    const int lc = lane & 15, lg = lane >> 4;
    const int wm = wid >> 2, wn = wid & 3;           // 2x4 wave grid

    const int gx = N >> 8;
    const int nwg = gridDim.x;
    int orig = blockIdx.x;
    int swz = ((nwg & 7) == 0) ? ((orig & 7) * (nwg >> 3) + (orig >> 3)) : orig;
    const long tile_m = (long)(swz / gx) * 256;
    const long tile_n = (long)(swz % gx) * 256;

    // stage all 4 half-tiles (A,B x rows 0-127 / 128-255) of one K-tile:
    // 8 gload_lds16/thread. LDS linear in slot s; source col-seg pre-swizzled.
    auto STAGE4 = [&](int buf, int kt) {
#pragma unroll
        for (int i = 0; i < 4; ++i) {
            int s = tid + i * 512;
            int r = s >> 3;
            int cs = (s & 7) ^ (r & 7);
            const bf16* ga = A  + (tile_m + r) * (long)K + kt * 64 + cs * 8;
            const bf16* gb = Bt + (tile_n + r) * (long)K + kt * 64 + cs * 8;
            gload_lds16(ga, (char*)As[buf] + s * 16);
            gload_lds16(gb, (char*)Bs[buf] + s * 16);
        }
    };
    auto LDA = [&](int buf, int mi, int ks) -> bf16x8 {
        int row = wm * 128 + mi * 16 + lc;
        int byte = (row * 128 + ks * 64 + lg * 16) ^ ((row & 7) << 4);
        return *(const bf16x8*)((const char*)As[buf] + byte);
    };
    auto LDB = [&](int buf, int nj, int ks) -> bf16x8 {
        int row = wn * 64 + nj * 16 + lc;
        int byte = (row * 128 + ks * 64 + lg * 16) ^ ((row & 7) << 4);
        return *(const bf16x8*)((const char*)Bs[buf] + byte);
    };

    const f32x4 fz = {0.f, 0.f, 0.f, 0.f};
    f32x4 acc[8][4];
#pragma unroll
    for (int i = 0; i < 8; ++i)
#pragma unroll
        for (int j = 0; j < 4; ++j) acc[i][j] = fz;

    const int nkt = K >> 6;                          // 16

#define BAR()   asm volatile("s_barrier" ::: "memory")
#define LGKM0() asm volatile("s_waitcnt lgkmcnt(0)" ::: "memory")

    // prologue: kt0 -> buf0, kt1 -> buf1; wait kt0 (8 of 16 outstanding)
    STAGE4(0, 0);
    STAGE4(1, 1);
    asm volatile("s_waitcnt vmcnt(8)" ::: "memory");
    BAR();

    for (int g = 0; g < nkt; ++g) {
        const int b = g & 1;
        bf16x8 alo[4][2], ahi[4][2], blo[2][2], bhi[2][2];
        // ---- phase 0: read alo(8), blo(4); MFMA Q0 = acc[0-3][0-1] ----
#pragma unroll
        for (int mi = 0; mi < 4; ++mi) { alo[mi][0] = LDA(b, mi, 0); alo[mi][1] = LDA(b, mi, 1); }
#pragma unroll
        for (int nj = 0; nj < 2; ++nj) { blo[nj][0] = LDB(b, nj, 0); blo[nj][1] = LDB(b, nj, 1); }
        BAR(); LGKM0();
        __builtin_amdgcn_s_setprio(1);
#pragma unroll
        for (int mi = 0; mi < 4; ++mi)
#pragma unroll
            for (int nj = 0; nj < 2; ++nj)
#pragma unroll
                for (int ks = 0; ks < 2; ++ks)
                    acc[mi][nj] = MFMA16(alo[mi][ks], blo[nj][ks], acc[mi][nj]);
        __builtin_amdgcn_s_setprio(0);
        BAR();
        // ---- phase 1: read bhi(4); MFMA Q1 = acc[0-3][2-3] ----
#pragma unroll
        for (int nj = 0; nj < 2; ++nj) { bhi[nj][0] = LDB(b, nj + 2, 0); bhi[nj][1] = LDB(b, nj + 2, 1); }
        BAR(); LGKM0();
        __builtin_amdgcn_s_setprio(1);
#pragma unroll
        for (int mi = 0; mi < 4; ++mi)
#pragma unroll
            for (int nj = 0; nj < 2; ++nj)
#pragma unroll
                for (int ks = 0; ks < 2; ++ks)
                    acc[mi][nj + 2] = MFMA16(alo[mi][ks], bhi[nj][ks], acc[mi][nj + 2]);
        __builtin_amdgcn_s_setprio(0);
        BAR();
        // ---- phase 2: read ahi(8); MFMA Q2 = acc[4-7][2-3] ----
#pragma unroll
        for (int mi = 0; mi < 4; ++mi) { ahi[mi][0] = LDA(b, mi + 4, 0); ahi[mi][1] = LDA(b, mi + 4, 1); }
        BAR(); LGKM0();
        __builtin_amdgcn_s_setprio(1);
#pragma unroll
        for (int mi = 0; mi < 4; ++mi)
#pragma unroll
            for (int nj = 0; nj < 2; ++nj)
#pragma unroll
                for (int ks = 0; ks < 2; ++ks)
                    acc[mi + 4][nj + 2] = MFMA16(ahi[mi][ks], bhi[nj][ks], acc[mi + 4][nj + 2]);
        __builtin_amdgcn_s_setprio(0);
        BAR();
        // ---- phase 3: stage K-tile g+2 into buf b (reads of b all done);
        //      vmcnt(8) = drain K-tile g+1's loads; MFMA Q3 = acc[4-7][0-1] ----
        {
            int ktS = g + 2 < nkt ? g + 2 : nkt - 1;   // tail: hot re-read, never read back
            STAGE4(b, ktS);
        }
        asm volatile("s_waitcnt vmcnt(8)" ::: "memory");
        BAR();
        __builtin_amdgcn_s_setprio(1);
#pragma unroll
        for (int mi = 0; mi < 4; ++mi)
#pragma unroll
            for (int nj = 0; nj < 2; ++nj)
#pragma unroll
                for (int ks = 0; ks < 2; ++ks)
                    acc[mi + 4][nj] = MFMA16(ahi[mi][ks], blo[nj][ks], acc[mi + 4][nj]);
        __builtin_amdgcn_s_setprio(0);
        BAR();
    }
    asm volatile("s_waitcnt vmcnt(0)" ::: "memory");   // DMA must not outlive block

#undef BAR
#undef LGKM0

    // ---- epilogue: C/D layout row=lg*4+rr, col=lc ----
#pragma unroll
    for (int mi = 0; mi < 8; ++mi)
#pragma unroll
        for (int nj = 0; nj < 4; ++nj)
#pragma unroll
            for (int rr = 0; rr < 4; ++rr) {
                long row = tile_m + wm * 128 + mi * 16 + lg * 4 + rr;
                long col = tile_n + wn * 64 + nj * 16 + lc;
                float v = acc[mi][nj][rr];
                if constexpr (OUT_BF16) Cb[row * N + col] = __float2bfloat16(v);
                else                    Cf[row * N + col] = v + bias[col];
            }
}

// ---------------- causal flash attention v6: single strip, heavy-first ----
__global__ __launch_bounds__(256, 2) void attn_fwd6(const bf16* __restrict__ qkv,
                                                    bf16* __restrict__ out) {
    const int bh = blockIdx.x;                 // 0..63
    const int p  = blockIdx.y;                 // 0..15
    const int s  = 15 - p;                     // strip index, heavy first
    const int b = bh >> 4, h = bh & 15;
    const int tid = threadIdx.x;
    const int lane = tid & 63, wid = tid >> 6;
    const int ln31 = lane & 31, hi = lane >> 5;
    const int ch = (lane >> 4) & 1, c16 = lane & 15;
    const long rowbase = (long)b * Ss;
    const int q0 = s * 128 + wid * 32;         // this wave's 32 q-rows
    const int nt = 2 * s + 2;                  // causal kv tiles
    const float CL2 = 0.18033688f;             // 0.125 * log2(e)

    __shared__ __align__(16) bf16 Ks[2][64 * 64];
    __shared__ __align__(16) bf16 Vs[2][64 * 64];

    const int sK0 = tid, sK1 = tid + 256;
    const int rK0 = sK0 >> 3, cK0 = ((sK0 & 7) ^ (rK0 & 7)) * 8;
    const int rK1 = sK1 >> 3, cK1 = ((sK1 & 7) ^ (rK1 & 7)) * 8;
    const int rV0 = ((sK0 >> 5) << 2) | ((sK0 >> 1) & 3);
    const int cV0 = ((((sK0 >> 3) & 3) << 1) | (sK0 & 1)) * 8;
    const int rV1 = ((sK1 >> 5) << 2) | ((sK1 >> 1) & 3);
    const int cV1 = ((((sK1 >> 3) & 3) << 1) | (sK1 & 1)) * 8;
    const bf16* gK0 = qkv + (rowbase + rK0) * (long)TD + h * HD + Dd + cK0;
    const bf16* gK1 = qkv + (rowbase + rK1) * (long)TD + h * HD + Dd + cK1;
    const bf16* gV0 = qkv + (rowbase + rV0) * (long)TD + h * HD + 2 * Dd + cV0;
    const bf16* gV1 = qkv + (rowbase + rV1) * (long)TD + h * HD + 2 * Dd + cV1;

    auto STAGE = [&](int buf, int kt) {
        const long o = (long)kt * 64 * TD;
        gload_lds16(gK0 + o, (char*)Ks[buf] + tid * 16);
        gload_lds16(gK1 + o, (char*)Ks[buf] + 4096 + tid * 16);
        gload_lds16(gV0 + o, (char*)Vs[buf] + tid * 16);
        gload_lds16(gV1 + o, (char*)Vs[buf] + 4096 + tid * 16);
    };

    bf16x8 qa[4];
#pragma unroll
    for (int dk = 0; dk < 4; ++dk)
        qa[dk] = *(const bf16x8*)(qkv + (rowbase + q0 + ln31) * (long)TD + h * HD + dk * 16 + hi * 8);

    f32x16 acc[2];
#pragma unroll
    for (int dt = 0; dt < 2; ++dt) acc[dt] = (f32x16)0.0f;
    float m2 = -3.0e38f;
    float l = 0.f;

    STAGE(0, 0);
    __syncthreads();

    for (int kt = 0; kt < nt; ++kt) {
        const int cur = kt & 1;
        if (kt + 1 < nt) STAGE(cur ^ 1, kt + 1);

        if (kt * 64 <= q0 + 31) {
            const char* kbp = (const char*)Ks[cur];
            const char* vbp = (const char*)Vs[cur];
            f32x16 sc[2];
            __builtin_amdgcn_s_setprio(1);
#pragma unroll
            for (int st = 0; st < 2; ++st) {
                f32x16 z = (f32x16)0.0f;
                const int row = st * 32 + ln31;
                const int sw = (row & 7) << 4;
#pragma unroll
                for (int dk = 0; dk < 4; ++dk) {
                    bf16x8 ka = *(const bf16x8*)(kbp + ((row * 128 + dk * 32 + hi * 16) ^ sw));
                    z = MFMA32(ka, qa[dk], z);
                }
                sc[st] = z;
            }
            __builtin_amdgcn_s_setprio(0);
            if (kt * 64 + 63 > q0) {
                const int qg = q0 + ln31;
                const int kbase = kt * 64 + 4 * hi;
#pragma unroll
                for (int st = 0; st < 2; ++st)
#pragma unroll
                    for (int r = 0; r < 16; ++r) {
                        int kg = kbase + st * 32 + (r & 3) + 8 * (r >> 2);
                        if (kg > qg) sc[st][r] = -3.0e38f;
                    }
            }
            float mx = sc[0][0];
#pragma unroll
            for (int r = 1; r < 16; ++r) mx = fmaxf(mx, sc[0][r]);
#pragma unroll
            for (int r = 0; r < 16; ++r) mx = fmaxf(mx, sc[1][r]);
            mx = fmaxf(mx, __shfl_xor(mx, 32));
            float pmax2 = mx * CL2;
            if (__ballot(pmax2 > m2 + 8.0f)) {
                float mnew = fmaxf(m2, pmax2);
                float sf = __builtin_amdgcn_exp2f(m2 - mnew);
                m2 = mnew;
                l *= sf;
#pragma unroll
                for (int r = 0; r < 16; ++r) {
                    float sfr = __shfl(sf, (r & 3) + 8 * (r >> 2) + 4 * hi);
                    acc[0][r] *= sfr;
                    acc[1][r] *= sfr;
                }
            }
            bf16x4 vl[4][2], vh[4][2];
            const unsigned vbase = lds_addr(vbp) + hi * 1024 + ch * 128 + c16 * 8;
#pragma unroll
            for (int ksg = 0; ksg < 4; ++ksg)
#pragma unroll
                for (int dt = 0; dt < 2; ++dt) {
                    asm volatile("ds_read_b64_tr_b16 %0, %2\n\t"
                                 "ds_read_b64_tr_b16 %1, %2 offset:512"
                                 : "=v"(vl[ksg][dt]), "=v"(vh[ksg][dt])
                                 : "v"(vbase + (unsigned)(ksg * 2048 + dt * 256)) : "memory");
                }
            const float mt = m2;
            float sum = 0.f;
            unsigned w[2][8];
#pragma unroll
            for (int st = 0; st < 2; ++st)
#pragma unroll
                for (int n = 0; n < 8; ++n) {
                    float e0 = __builtin_amdgcn_exp2f(fmaf(sc[st][2 * n],     CL2, -mt));
                    float e1 = __builtin_amdgcn_exp2f(fmaf(sc[st][2 * n + 1], CL2, -mt));
                    sum += e0 + e1;
                    w[st][n] = pack2bf(e0, e1);
                }
            sum += __shfl_xor(sum, 32);
            l += sum;
            union { unsigned u[4]; bf16x8 v; } pa[4];
#pragma unroll
            for (int ksg = 0; ksg < 4; ++ksg) {
                const int st = ksg >> 1, kl = ksg & 1;
                unsigned x0 = w[st][4 * kl],     y0 = w[st][4 * kl + 2];
                unsigned x1 = w[st][4 * kl + 1], y1 = w[st][4 * kl + 3];
                asm volatile("v_permlane32_swap_b32 %0, %1" : "+v"(x0), "+v"(y0));
                asm volatile("v_permlane32_swap_b32 %0, %1" : "+v"(x1), "+v"(y1));
                pa[ksg].u[0] = x0; pa[ksg].u[1] = x1; pa[ksg].u[2] = y0; pa[ksg].u[3] = y1;
            }
            asm volatile("s_waitcnt lgkmcnt(0)" ::: "memory");
            __builtin_amdgcn_sched_barrier(0);
            __builtin_amdgcn_s_setprio(1);
#pragma unroll
            for (int ksg = 0; ksg < 4; ++ksg)
#pragma unroll
                for (int dt = 0; dt < 2; ++dt) {
                    bf16x8 vb = __builtin_shufflevector(vl[ksg][dt], vh[ksg][dt],
                                                        0, 1, 2, 3, 4, 5, 6, 7);
                    acc[dt] = MFMA32(pa[ksg].v, vb, acc[dt]);
                }
            __builtin_amdgcn_s_setprio(0);
        }

        __syncthreads();
    }

    float invl = 1.f / l;
#pragma unroll
    for (int r = 0; r < 16; ++r) {
        float ir = __shfl(invl, (r & 3) + 8 * (r >> 2) + 4 * hi);
        long orow = rowbase + q0 + (r & 3) + 8 * (r >> 2) + 4 * hi;
#pragma unroll
        for (int dt = 0; dt < 2; ++dt)
            out[orow * Dd + h * HD + dt * 32 + ln31] = __float2bfloat16(acc[dt][r] * ir);
    }
}

extern "C" void kernel_launch(void* const* d_in, const int* in_sizes, int n_in,
                              void* d_out, int out_size, void* d_ws, size_t ws_size,
                              hipStream_t stream) {
    const float* x    = (const float*)d_in[0];
    const float* Wqkv = (const float*)d_in[1];
    const float* Wo_w = (const float*)d_in[2];
    const float* Wo_b = (const float*)d_in[3];
    float* out = (float*)d_out;

    const size_t MB = 1ull << 20;
    char* ws = (char*)d_ws;
    bf16* xb    = (bf16*)(ws);               // 16 MB; reused as attn output
    bf16* wqkvb = (bf16*)(ws + 16 * MB);     // 6 MB
    bf16* wob   = (bf16*)(ws + 22 * MB);     // 2 MB
    bf16* qkv   = (bf16*)(ws + 24 * MB);     // 48 MB
    bf16* attnb = xb;

    cast_f32_bf16<<<8192, 256, 0, stream>>>(x, xb, Mrows * Dd / 4);
    cast_f32_bf16<<<3072, 256, 0, stream>>>(Wqkv, wqkvb, TD * Dd / 4);
    cast_f32_bf16<<<1024, 256, 0, stream>>>(Wo_w, wob, Dd * Dd / 4);

    // qkv = x @ Wqkv^T : grid 384
    gemm256<true><<<(Mrows / 256) * (TD / 256), 512, 0, stream>>>(
        xb, wqkvb, qkv, nullptr, nullptr, Mrows, TD, Dd);

    attn_fwd6<<<dim3(Bb * Hh, 16), 256, 0, stream>>>(qkv, attnb);

    // out = attn @ Wo^T + b : grid 128
    gemm256<false><<<(Mrows / 256) * (Dd / 256), 512, 0, stream>>>(
        attnb, wob, nullptr, out, Wo_b, Mrows, Dd, Dd);
}

// Round 10
// 167.551 us; speedup vs baseline: 1.1058x; 1.1058x over previous
//
#include <hip/hip_runtime.h>
#include <hip/hip_bf16.h>

using bf16 = __hip_bfloat16;
typedef __attribute__((ext_vector_type(8))) short bf16x8;
typedef __attribute__((ext_vector_type(4))) short bf16x4;
typedef __attribute__((ext_vector_type(4))) float f32x4;
typedef __attribute__((ext_vector_type(16))) float f32x16;

static constexpr int Bb = 4, Ss = 2048, Dd = 1024, Hh = 16, HD = 64;
static constexpr int TD = 3 * Dd;            // 3072
static constexpr int Mrows = Bb * Ss;        // 8192

#define MFMA16(a, b, c) __builtin_amdgcn_mfma_f32_16x16x32_bf16((a), (b), (c), 0, 0, 0)
#define MFMA32(a, b, c) __builtin_amdgcn_mfma_f32_32x32x16_bf16((a), (b), (c), 0, 0, 0)

__device__ __forceinline__ void gload_lds16(const void* g, void* l) {
    __builtin_amdgcn_global_load_lds(
        (const __attribute__((address_space(1))) void*)g,
        (__attribute__((address_space(3))) void*)l, 16, 0, 0);
}

__device__ __forceinline__ unsigned lds_addr(const void* p) {
    return (unsigned)(unsigned long long)(const __attribute__((address_space(3))) char*)p;
}

__device__ __forceinline__ unsigned pack2bf(float a, float b) {
    bf16 x = __float2bfloat16(a), y = __float2bfloat16(b);
    return (unsigned)(*(unsigned short*)&x) | ((unsigned)(*(unsigned short*)&y) << 16);
}

// ---------------- fused cast fp32 -> bf16 (x, Wqkv, Wo in one launch) ------
__global__ void cast_all(const float* __restrict__ x, const float* __restrict__ w1,
                         const float* __restrict__ w2, bf16* __restrict__ xb,
                         bf16* __restrict__ w1b, bf16* __restrict__ w2b) {
    int i = blockIdx.x * blockDim.x + threadIdx.x;   // 4-elem groups
    const float* src; bf16* dst; int off;
    if (i < 2097152)      { src = x;  dst = xb;  off = i; }
    else if (i < 2883584) { src = w1; dst = w1b; off = i - 2097152; }
    else                  { src = w2; dst = w2b; off = i - 2883584; }
    float4 v = ((const float4*)src)[off];
    uint2 o;
    o.x = pack2bf(v.x, v.y);
    o.y = pack2bf(v.z, v.w);
    *(uint2*)(dst + 4l * off) = o;
}

// ---------------- GEMM 256x128, BK=64, 8 waves, 4-phase interleave ---------
// C[m,n] = sum_k A[m,k]*Bt[n,k]. Tile sized so grids fill CUs EXACTLY:
// GEMM1 768 blocks = 3 gens, GEMM2 256 = 1 gen (1 block/CU at 96KB LDS).
// Per K-tile g (buf b=g&1): top {vmcnt(0); s_barrier} (buf b staged last
// iter, ~3 phases of slack); then 4 phases of {ds_reads(8/4/4/0) + 2
// staging gloads for g+1; s_barrier; lgkmcnt(0); setprio(1); 8 MFMA;
// setprio(0); s_barrier}. T2 XOR-swizzle throughout (conflicts = 0).
template<bool OUT_BF16>
__global__ __launch_bounds__(512, 1) void gemm256x128(
    const bf16* __restrict__ A, const bf16* __restrict__ Bt,
    bf16* __restrict__ Cb, float* __restrict__ Cf, const float* __restrict__ bias,
    int M, int N, int K)
{
    __shared__ __align__(16) bf16 As[2][256 * 64];   // 64 KB
    __shared__ __align__(16) bf16 Bs[2][128 * 64];   // 32 KB
    const int tid = threadIdx.x;
    const int lane = tid & 63;
    const int wid = tid >> 6;
    const int lc = lane & 15, lg = lane >> 4;
    const int wm = wid >> 1, wn = wid & 1;           // 4x2 wave grid

    const int gx = N >> 7;                           // tiles along N (128)
    const int nwg = gridDim.x;
    int orig = blockIdx.x;
    int swz = ((nwg & 7) == 0) ? ((orig & 7) * (nwg >> 3) + (orig >> 3)) : orig;
    const long tile_m = (long)(swz / gx) * 256;
    const long tile_n = (long)(swz % gx) * 128;

    // staging: LDS linear in slot s, global col-seg pre-swizzled (G21)
    auto STAGE_A = [&](int buf, int kt, int i) {     // i = 0..3
        int s = tid + i * 512;
        int r = s >> 3;
        int cs = (s & 7) ^ (r & 7);
        gload_lds16(A + (tile_m + r) * (long)K + kt * 64 + cs * 8,
                    (char*)As[buf] + s * 16);
    };
    auto STAGE_B = [&](int buf, int kt, int i) {     // i = 0..1
        int s = tid + i * 512;
        int r = s >> 3;
        int cs = (s & 7) ^ (r & 7);
        gload_lds16(Bt + (tile_n + r) * (long)K + kt * 64 + cs * 8,
                    (char*)Bs[buf] + s * 16);
    };
    auto LDA = [&](int buf, int mi, int ks) -> bf16x8 {
        int row = wm * 64 + mi * 16 + lc;
        int byte = (row * 128 + ks * 64 + lg * 16) ^ ((row & 7) << 4);
        return *(const bf16x8*)((const char*)As[buf] + byte);
    };
    auto LDB = [&](int buf, int nj, int ks) -> bf16x8 {
        int row = wn * 64 + nj * 16 + lc;
        int byte = (row * 128 + ks * 64 + lg * 16) ^ ((row & 7) << 4);
        return *(const bf16x8*)((const char*)Bs[buf] + byte);
    };

    const f32x4 fz = {0.f, 0.f, 0.f, 0.f};
    f32x4 acc[4][4];
#pragma unroll
    for (int i = 0; i < 4; ++i)
#pragma unroll
        for (int j = 0; j < 4; ++j) acc[i][j] = fz;

    const int nkt = K >> 6;                          // 16

#define BAR()   asm volatile("s_barrier" ::: "memory")
#define LGKM0() asm volatile("s_waitcnt lgkmcnt(0)" ::: "memory")

    // prologue: stage K-tile 0 into buf 0 (6 loads)
    STAGE_A(0, 0, 0); STAGE_A(0, 0, 1); STAGE_A(0, 0, 2); STAGE_A(0, 0, 3);
    STAGE_B(0, 0, 0); STAGE_B(0, 0, 1);

    for (int g = 0; g < nkt; ++g) {
        const int b = g & 1;
        const bool pf = (g + 1 < nkt);
        asm volatile("s_waitcnt vmcnt(0)" ::: "memory");   // buf b landed
        BAR();                                             // block-wide visible
        bf16x8 a0[2][2], a1[2][2], b0[2][2], b1[2][2];
        // ---- P0: read a(mi0-1), b(nj0-1); stage A chunks 0,1; MFMA Q00 ----
#pragma unroll
        for (int mi = 0; mi < 2; ++mi) { a0[mi][0] = LDA(b, mi, 0); a0[mi][1] = LDA(b, mi, 1); }
#pragma unroll
        for (int nj = 0; nj < 2; ++nj) { b0[nj][0] = LDB(b, nj, 0); b0[nj][1] = LDB(b, nj, 1); }
        if (pf) { STAGE_A(b ^ 1, g + 1, 0); STAGE_A(b ^ 1, g + 1, 1); }
        BAR(); LGKM0();
        __builtin_amdgcn_s_setprio(1);
#pragma unroll
        for (int mi = 0; mi < 2; ++mi)
#pragma unroll
            for (int nj = 0; nj < 2; ++nj)
#pragma unroll
                for (int ks = 0; ks < 2; ++ks)
                    acc[mi][nj] = MFMA16(a0[mi][ks], b0[nj][ks], acc[mi][nj]);
        __builtin_amdgcn_s_setprio(0);
        BAR();
        // ---- P1: read b(nj2-3); stage A chunks 2,3; MFMA Q01 ----
#pragma unroll
        for (int nj = 0; nj < 2; ++nj) { b1[nj][0] = LDB(b, nj + 2, 0); b1[nj][1] = LDB(b, nj + 2, 1); }
        if (pf) { STAGE_A(b ^ 1, g + 1, 2); STAGE_A(b ^ 1, g + 1, 3); }
        BAR(); LGKM0();
        __builtin_amdgcn_s_setprio(1);
#pragma unroll
        for (int mi = 0; mi < 2; ++mi)
#pragma unroll
            for (int nj = 0; nj < 2; ++nj)
#pragma unroll
                for (int ks = 0; ks < 2; ++ks)
                    acc[mi][nj + 2] = MFMA16(a0[mi][ks], b1[nj][ks], acc[mi][nj + 2]);
        __builtin_amdgcn_s_setprio(0);
        BAR();
        // ---- P2: read a(mi2-3); stage B chunks 0,1; MFMA Q11 ----
#pragma unroll
        for (int mi = 0; mi < 2; ++mi) { a1[mi][0] = LDA(b, mi + 2, 0); a1[mi][1] = LDA(b, mi + 2, 1); }
        if (pf) { STAGE_B(b ^ 1, g + 1, 0); STAGE_B(b ^ 1, g + 1, 1); }
        BAR(); LGKM0();
        __builtin_amdgcn_s_setprio(1);
#pragma unroll
        for (int mi = 0; mi < 2; ++mi)
#pragma unroll
            for (int nj = 0; nj < 2; ++nj)
#pragma unroll
                for (int ks = 0; ks < 2; ++ks)
                    acc[mi + 2][nj + 2] = MFMA16(a1[mi][ks], b1[nj][ks], acc[mi + 2][nj + 2]);
        __builtin_amdgcn_s_setprio(0);
        BAR();
        // ---- P3: no reads; MFMA Q10 (regs only) ----
        __builtin_amdgcn_s_setprio(1);
#pragma unroll
        for (int mi = 0; mi < 2; ++mi)
#pragma unroll
            for (int nj = 0; nj < 2; ++nj)
#pragma unroll
                for (int ks = 0; ks < 2; ++ks)
                    acc[mi + 2][nj] = MFMA16(a1[mi][ks], b0[nj][ks], acc[mi + 2][nj]);
        __builtin_amdgcn_s_setprio(0);
    }
    asm volatile("s_waitcnt vmcnt(0)" ::: "memory");

#undef BAR
#undef LGKM0

    // ---- epilogue: C/D layout row=lg*4+rr, col=lc ----
#pragma unroll
    for (int mi = 0; mi < 4; ++mi)
#pragma unroll
        for (int nj = 0; nj < 4; ++nj)
#pragma unroll
            for (int rr = 0; rr < 4; ++rr) {
                long row = tile_m + wm * 64 + mi * 16 + lg * 4 + rr;
                long col = tile_n + wn * 64 + nj * 16 + lc;
                float v = acc[mi][nj][rr];
                if constexpr (OUT_BF16) Cb[row * N + col] = __float2bfloat16(v);
                else                    Cf[row * N + col] = v + bias[col];
            }
}

// ---------------- causal flash attention v6: single strip, heavy-first ----
__global__ __launch_bounds__(256, 2) void attn_fwd6(const bf16* __restrict__ qkv,
                                                    bf16* __restrict__ out) {
    const int bh = blockIdx.x;                 // 0..63
    const int p  = blockIdx.y;                 // 0..15
    const int s  = 15 - p;                     // strip index, heavy first
    const int b = bh >> 4, h = bh & 15;
    const int tid = threadIdx.x;
    const int lane = tid & 63, wid = tid >> 6;
    const int ln31 = lane & 31, hi = lane >> 5;
    const int ch = (lane >> 4) & 1, c16 = lane & 15;
    const long rowbase = (long)b * Ss;
    const int q0 = s * 128 + wid * 32;         // this wave's 32 q-rows
    const int nt = 2 * s + 2;                  // causal kv tiles
    const float CL2 = 0.18033688f;             // 0.125 * log2(e)

    __shared__ __align__(16) bf16 Ks[2][64 * 64];
    __shared__ __align__(16) bf16 Vs[2][64 * 64];

    const int sK0 = tid, sK1 = tid + 256;
    const int rK0 = sK0 >> 3, cK0 = ((sK0 & 7) ^ (rK0 & 7)) * 8;
    const int rK1 = sK1 >> 3, cK1 = ((sK1 & 7) ^ (rK1 & 7)) * 8;
    const int rV0 = ((sK0 >> 5) << 2) | ((sK0 >> 1) & 3);
    const int cV0 = ((((sK0 >> 3) & 3) << 1) | (sK0 & 1)) * 8;
    const int rV1 = ((sK1 >> 5) << 2) | ((sK1 >> 1) & 3);
    const int cV1 = ((((sK1 >> 3) & 3) << 1) | (sK1 & 1)) * 8;
    const bf16* gK0 = qkv + (rowbase + rK0) * (long)TD + h * HD + Dd + cK0;
    const bf16* gK1 = qkv + (rowbase + rK1) * (long)TD + h * HD + Dd + cK1;
    const bf16* gV0 = qkv + (rowbase + rV0) * (long)TD + h * HD + 2 * Dd + cV0;
    const bf16* gV1 = qkv + (rowbase + rV1) * (long)TD + h * HD + 2 * Dd + cV1;

    auto STAGE = [&](int buf, int kt) {
        const long o = (long)kt * 64 * TD;
        gload_lds16(gK0 + o, (char*)Ks[buf] + tid * 16);
        gload_lds16(gK1 + o, (char*)Ks[buf] + 4096 + tid * 16);
        gload_lds16(gV0 + o, (char*)Vs[buf] + tid * 16);
        gload_lds16(gV1 + o, (char*)Vs[buf] + 4096 + tid * 16);
    };

    bf16x8 qa[4];
#pragma unroll
    for (int dk = 0; dk < 4; ++dk)
        qa[dk] = *(const bf16x8*)(qkv + (rowbase + q0 + ln31) * (long)TD + h * HD + dk * 16 + hi * 8);

    f32x16 acc[2];
#pragma unroll
    for (int dt = 0; dt < 2; ++dt) acc[dt] = (f32x16)0.0f;
    float m2 = -3.0e38f;
    float l = 0.f;

    STAGE(0, 0);
    __syncthreads();

    for (int kt = 0; kt < nt; ++kt) {
        const int cur = kt & 1;
        if (kt + 1 < nt) STAGE(cur ^ 1, kt + 1);

        if (kt * 64 <= q0 + 31) {
            const char* kbp = (const char*)Ks[cur];
            const char* vbp = (const char*)Vs[cur];
            f32x16 sc[2];
            __builtin_amdgcn_s_setprio(1);
#pragma unroll
            for (int st = 0; st < 2; ++st) {
                f32x16 z = (f32x16)0.0f;
                const int row = st * 32 + ln31;
                const int sw = (row & 7) << 4;
#pragma unroll
                for (int dk = 0; dk < 4; ++dk) {
                    bf16x8 ka = *(const bf16x8*)(kbp + ((row * 128 + dk * 32 + hi * 16) ^ sw));
                    z = MFMA32(ka, qa[dk], z);
                }
                sc[st] = z;
            }
            __builtin_amdgcn_s_setprio(0);
            if (kt * 64 + 63 > q0) {
                const int qg = q0 + ln31;
                const int kbase = kt * 64 + 4 * hi;
#pragma unroll
                for (int st = 0; st < 2; ++st)
#pragma unroll
                    for (int r = 0; r < 16; ++r) {
                        int kg = kbase + st * 32 + (r & 3) + 8 * (r >> 2);
                        if (kg > qg) sc[st][r] = -3.0e38f;
                    }
            }
            float mx = sc[0][0];
#pragma unroll
            for (int r = 1; r < 16; ++r) mx = fmaxf(mx, sc[0][r]);
#pragma unroll
            for (int r = 0; r < 16; ++r) mx = fmaxf(mx, sc[1][r]);
            mx = fmaxf(mx, __shfl_xor(mx, 32));
            float pmax2 = mx * CL2;
            if (__ballot(pmax2 > m2 + 8.0f)) {
                float mnew = fmaxf(m2, pmax2);
                float sf = __builtin_amdgcn_exp2f(m2 - mnew);
                m2 = mnew;
                l *= sf;
#pragma unroll
                for (int r = 0; r < 16; ++r) {
                    float sfr = __shfl(sf, (r & 3) + 8 * (r >> 2) + 4 * hi);
                    acc[0][r] *= sfr;
                    acc[1][r] *= sfr;
                }
            }
            bf16x4 vl[4][2], vh[4][2];
            const unsigned vbase = lds_addr(vbp) + hi * 1024 + ch * 128 + c16 * 8;
#pragma unroll
            for (int ksg = 0; ksg < 4; ++ksg)
#pragma unroll
                for (int dt = 0; dt < 2; ++dt) {
                    asm volatile("ds_read_b64_tr_b16 %0, %2\n\t"
                                 "ds_read_b64_tr_b16 %1, %2 offset:512"
                                 : "=v"(vl[ksg][dt]), "=v"(vh[ksg][dt])
                                 : "v"(vbase + (unsigned)(ksg * 2048 + dt * 256)) : "memory");
                }
            const float mt = m2;
            float sum = 0.f;
            unsigned w[2][8];
#pragma unroll
            for (int st = 0; st < 2; ++st)
#pragma unroll
                for (int n = 0; n < 8; ++n) {
                    float e0 = __builtin_amdgcn_exp2f(fmaf(sc[st][2 * n],     CL2, -mt));
                    float e1 = __builtin_amdgcn_exp2f(fmaf(sc[st][2 * n + 1], CL2, -mt));
                    sum += e0 + e1;
                    w[st][n] = pack2bf(e0, e1);
                }
            sum += __shfl_xor(sum, 32);
            l += sum;
            union { unsigned u[4]; bf16x8 v; } pa[4];
#pragma unroll
            for (int ksg = 0; ksg < 4; ++ksg) {
                const int st = ksg >> 1, kl = ksg & 1;
                unsigned x0 = w[st][4 * kl],     y0 = w[st][4 * kl + 2];
                unsigned x1 = w[st][4 * kl + 1], y1 = w[st][4 * kl + 3];
                asm volatile("v_permlane32_swap_b32 %0, %1" : "+v"(x0), "+v"(y0));
                asm volatile("v_permlane32_swap_b32 %0, %1" : "+v"(x1), "+v"(y1));
                pa[ksg].u[0] = x0; pa[ksg].u[1] = x1; pa[ksg].u[2] = y0; pa[ksg].u[3] = y1;
            }
            asm volatile("s_waitcnt lgkmcnt(0)" ::: "memory");
            __builtin_amdgcn_sched_barrier(0);
            __builtin_amdgcn_s_setprio(1);
#pragma unroll
            for (int ksg = 0; ksg < 4; ++ksg)
#pragma unroll
                for (int dt = 0; dt < 2; ++dt) {
                    bf16x8 vb = __builtin_shufflevector(vl[ksg][dt], vh[ksg][dt],
                                                        0, 1, 2, 3, 4, 5, 6, 7);
                    acc[dt] = MFMA32(pa[ksg].v, vb, acc[dt]);
                }
            __builtin_amdgcn_s_setprio(0);
        }

        __syncthreads();
    }

    float invl = 1.f / l;
#pragma unroll
    for (int r = 0; r < 16; ++r) {
        float ir = __shfl(invl, (r & 3) + 8 * (r >> 2) + 4 * hi);
        long orow = rowbase + q0 + (r & 3) + 8 * (r >> 2) + 4 * hi;
#pragma unroll
        for (int dt = 0; dt < 2; ++dt)
            out[orow * Dd + h * HD + dt * 32 + ln31] = __float2bfloat16(acc[dt][r] * ir);
    }
}

extern "C" void kernel_launch(void* const* d_in, const int* in_sizes, int n_in,
                              void* d_out, int out_size, void* d_ws, size_t ws_size,
                              hipStream_t stream) {
    const float* x    = (const float*)d_in[0];
    const float* Wqkv = (const float*)d_in[1];
    const float* Wo_w = (const float*)d_in[2];
    const float* Wo_b = (const float*)d_in[3];
    float* out = (float*)d_out;

    const size_t MB = 1ull << 20;
    char* ws = (char*)d_ws;
    bf16* xb    = (bf16*)(ws);               // 16 MB; reused as attn output
    bf16* wqkvb = (bf16*)(ws + 16 * MB);     // 6 MB
    bf16* wob   = (bf16*)(ws + 22 * MB);     // 2 MB
    bf16* qkv   = (bf16*)(ws + 24 * MB);     // 48 MB
    bf16* attnb = xb;

    cast_all<<<12288, 256, 0, stream>>>(x, Wqkv, Wo_w, xb, wqkvb, wob);

    // qkv = x @ Wqkv^T : grid 32*24 = 768 = exactly 3 generations
    gemm256x128<true><<<(Mrows / 256) * (TD / 128), 512, 0, stream>>>(
        xb, wqkvb, qkv, nullptr, nullptr, Mrows, TD, Dd);

    attn_fwd6<<<dim3(Bb * Hh, 16), 256, 0, stream>>>(qkv, attnb);

    // out = attn @ Wo^T + b : grid 32*8 = 256 = exactly 1 generation
    gemm256x128<false><<<(Mrows / 256) * (Dd / 128), 512, 0, stream>>>(
        attnb, wob, nullptr, out, Wo_b, Mrows, Dd, Dd);
}